// Round 1
// baseline (18730.020 us; speedup 1.0000x reference)
//
#include <hip/hip_runtime.h>
#include <math.h>

#define B_ 40
#define L_ 1000
#define H_ 512
#define A_ 300
#define T_ 20
#define E_ 300
#define V_ 78864
#define CIN_ 1624   // E + H + A + H
#define START_ 2

__device__ __forceinline__ float sigm(float x){ return 1.0f/(1.0f+expf(-x)); }

__device__ __forceinline__ float waveMax(float v){
#pragma unroll
  for(int o=32;o>0;o>>=1) v=fmaxf(v,__shfl_down(v,o));
  return v;
}
__device__ __forceinline__ float waveSum(float v){
#pragma unroll
  for(int o=32;o>0;o>>=1) v+=__shfl_down(v,o);
  return v;
}

// ---- positional encoding table [T,512] ----
__global__ void k_pe(float* __restrict__ pe){
  int t=blockIdx.x, d=threadIdx.x;
  float ex=(float)(2*(d>>1))/512.0f;
  float ang=(float)t/powf(10000.0f,ex);
  pe[t*H_+d]=(d&1)?cosf(ang):sinf(ang);
}

// ---- copyK[b,l,a] = tanh(enc[b,l,:] . copy_W[a,:] + copy_b[a]) ----
__global__ __launch_bounds__(320) void k_copyk(const float* __restrict__ enc,
    const float* __restrict__ W, const float* __restrict__ bias, float* __restrict__ out){
  __shared__ float xs[H_];
  int row=blockIdx.x, tid=threadIdx.x;
  for(int k=tid;k<H_;k+=320) xs[k]=enc[(long)row*H_+k];
  __syncthreads();
  if(tid<A_){
    float acc=bias[tid];
    const float4* wr=(const float4*)(W+(long)tid*H_);
#pragma unroll 4
    for(int i=0;i<H_/4;i++){ float4 w=wr[i];
      acc+=xs[4*i]*w.x+xs[4*i+1]*w.y+xs[4*i+2]*w.z+xs[4*i+3]*w.w; }
    out[(long)row*A_+tid]=tanhf(acc);
  }
}

// ---- generic LSTM cell: grid (8, B); block 256 = 4 gates x 64 units ----
template<int XD, bool GATHER>
__global__ __launch_bounds__(256) void k_lstm(const float* __restrict__ xsrc,
    const int* __restrict__ inp, const float* __restrict__ embed, int t,
    const float* __restrict__ hr, const float* __restrict__ cr,
    float* __restrict__ hw, float* __restrict__ cw,
    const float* __restrict__ Wih, const float* __restrict__ Whh, const float* __restrict__ bias){
  __shared__ float xs[XD], hs[H_], g4[256];
  int b=blockIdx.y, hb=blockIdx.x, tid=threadIdx.x;
  const float* xr;
  if constexpr(GATHER){
    int si=(t==0)?START_:inp[b*T_+t-1];
    xr=embed+(long)si*XD;
  } else {
    xr=xsrc+(long)b*XD;
  }
  for(int k=tid;k<XD;k+=256) xs[k]=xr[k];
  for(int k=tid;k<H_;k+=256) hs[k]=hr[b*H_+k];
  __syncthreads();
  int gate=tid>>6, u=(hb<<6)+(tid&63), row=gate*H_+u;
  float acc=bias[row];
  const float4* wi=(const float4*)(Wih+(long)row*XD);
#pragma unroll 4
  for(int i=0;i<XD/4;i++){ float4 w=wi[i];
    acc+=xs[4*i]*w.x+xs[4*i+1]*w.y+xs[4*i+2]*w.z+xs[4*i+3]*w.w; }
  const float4* wh=(const float4*)(Whh+(long)row*H_);
#pragma unroll 4
  for(int i=0;i<H_/4;i++){ float4 w=wh[i];
    acc+=hs[4*i]*w.x+hs[4*i+1]*w.y+hs[4*i+2]*w.z+hs[4*i+3]*w.w; }
  g4[tid]=acc;
  __syncthreads();
  if(tid<64){
    int uu=(hb<<6)+tid;
    float gi=g4[tid],gf=g4[64+tid],gg=g4[128+tid],go=g4[192+tid];
    float c=cr[b*H_+uu];
    float cn=sigm(gf)*c+sigm(gi)*tanhf(gg);
    hw[b*H_+uu]=sigm(go)*tanhf(cn);
    cw[b*H_+uu]=cn;
  }
}

// ---- dec_in[b,d] = concat(emb,eh2,att,sel) . in_W[d,:] + in_b[d] + pe[t,d] ----
__global__ __launch_bounds__(256) void k_decin(const int* __restrict__ inp,
    const float* __restrict__ embed, int t,
    const float* __restrict__ eh2, const float* __restrict__ attprev,
    const float* __restrict__ selpart,
    const float* __restrict__ W, const float* __restrict__ bias,
    const float* __restrict__ pe, float* __restrict__ out){
  __shared__ float xs[CIN_];
  int b=blockIdx.y, tid=threadIdx.x;
  int si=(t==0)?START_:inp[b*T_+t-1];
  for(int k=tid;k<CIN_;k+=256){
    float v;
    if(k<E_) v=embed[(long)si*E_+k];
    else if(k<E_+H_) v=eh2[b*H_+k-E_];
    else if(k<E_+H_+A_) v=attprev[b*A_+k-(E_+H_)];
    else{
      int h=k-(E_+H_+A_);
      float s=0.f;
#pragma unroll
      for(int j=0;j<8;j++) s+=selpart[(b*8+j)*H_+h];
      v=s;
    }
    xs[k]=v;
  }
  __syncthreads();
  int d=blockIdx.x*256+tid;
  float acc=bias[d]+pe[t*H_+d];
  const float4* wr=(const float4*)(W+(long)d*CIN_);
#pragma unroll 2
  for(int i=0;i<CIN_/4;i++){ float4 w=wr[i];
    acc+=xs[4*i]*w.x+xs[4*i+1]*w.y+xs[4*i+2]*w.z+xs[4*i+3]*w.w; }
  out[b*H_+d]=acc;
}

// ---- q = h@Wq.T + bq ; qk[b,h] = sum_a q[a]*Wk[a,h] ----
__global__ __launch_bounds__(512) void k_q(const float* __restrict__ h,
    const float* __restrict__ Wq, const float* __restrict__ bq,
    const float* __restrict__ Wk, float* __restrict__ qk){
  __shared__ float hs[H_], qs[A_];
  int b=blockIdx.x, tid=threadIdx.x;
  hs[tid]=h[b*H_+tid];
  __syncthreads();
  if(tid<A_){
    float acc=bq[tid];
    const float4* wr=(const float4*)(Wq+(long)tid*H_);
#pragma unroll 4
    for(int i=0;i<H_/4;i++){ float4 w=wr[i];
      acc+=hs[4*i]*w.x+hs[4*i+1]*w.y+hs[4*i+2]*w.z+hs[4*i+3]*w.w; }
    qs[tid]=acc;
  }
  __syncthreads();
  float acc=0.f;
  for(int a=0;a<A_;a++) acc+=qs[a]*Wk[a*H_+tid];
  qk[b*H_+tid]=acc;
}

// ---- s[b,l] = qk[b,:] . enc[b,l,:], masked ----
__global__ __launch_bounds__(128) void k_scores(const float* __restrict__ qk,
    const float* __restrict__ enc, const unsigned char* __restrict__ mask,
    float* __restrict__ s){
  __shared__ float qs[H_];
  int b=blockIdx.y, tid=threadIdx.x;
  for(int k=tid;k<H_;k+=128) qs[k]=qk[b*H_+k];
  __syncthreads();
  int l=blockIdx.x*128+tid;
  if(l<L_){
    float acc=0.f;
    const float4* er=(const float4*)(enc+((long)(b*L_+l))*H_);
#pragma unroll 4
    for(int i=0;i<H_/4;i++){ float4 e=er[i];
      acc+=qs[4*i]*e.x+qs[4*i+1]*e.y+qs[4*i+2]*e.z+qs[4*i+3]*e.w; }
    s[b*L_+l]=mask[b*L_+l]?-1e9f:acc;
  }
}

// ---- ctx partial: softmax(s) folded in; part[b,j,h] = sum_{l in chunk j} p_l * enc[b,l,h] ----
__global__ __launch_bounds__(512) void k_ctx(const float* __restrict__ s,
    const float* __restrict__ enc, float* __restrict__ part){
  __shared__ float e[L_];
  __shared__ float redm[8], reds[8];
  int b=blockIdx.y, j=blockIdx.x, tid=threadIdx.x;
  float lm=-3.0e38f;
  for(int l=tid;l<L_;l+=512){ float v=s[b*L_+l]; e[l]=v; lm=fmaxf(lm,v); }
  lm=waveMax(lm); if((tid&63)==0) redm[tid>>6]=lm;
  __syncthreads();
  float m=redm[0];
#pragma unroll
  for(int w2=1;w2<8;w2++) m=fmaxf(m,redm[w2]);
  float ls=0.f;
  for(int l=tid;l<L_;l+=512){ float ex=expf(e[l]-m); e[l]=ex; ls+=ex; }
  ls=waveSum(ls); if((tid&63)==0) reds[tid>>6]=ls;
  __syncthreads();
  float S=0.f;
#pragma unroll
  for(int w2=0;w2<8;w2++) S+=reds[w2];
  float inv=1.0f/S;
  float acc=0.f;
  int l0=j*125;
  for(int l=l0;l<l0+125;l++) acc+=e[l]*enc[((long)(b*L_+l))*H_+tid];
  part[(b*8+j)*H_+tid]=acc*inv;
}

// ---- att[b,a] = ctx . Wv[a,:] + bv (+ attprev) ----
template<bool ADD>
__global__ __launch_bounds__(512) void k_atto(const float* __restrict__ part,
    const float* __restrict__ Wv, const float* __restrict__ bv,
    const float* __restrict__ attprev, float* __restrict__ out){
  __shared__ float cs[H_];
  int b=blockIdx.x, tid=threadIdx.x;
  float c=0.f;
#pragma unroll
  for(int j=0;j<8;j++) c+=part[(b*8+j)*H_+tid];
  cs[tid]=c;
  __syncthreads();
  if(tid<A_){
    float acc=bv[tid];
    const float4* wr=(const float4*)(Wv+(long)tid*H_);
#pragma unroll 4
    for(int i=0;i<H_/4;i++){ float4 w=wr[i];
      acc+=cs[4*i]*w.x+cs[4*i+1]*w.y+cs[4*i+2]*w.z+cs[4*i+3]*w.w; }
    if constexpr(ADD) acc+=attprev[b*A_+tid];
    out[b*A_+tid]=acc;
  }
}

// ---- copy scores: s[b,l] = att . copyK[b,l,:], masked ----
__global__ __launch_bounds__(128) void k_copysc(const float* __restrict__ att,
    const float* __restrict__ ck, const unsigned char* __restrict__ mask,
    float* __restrict__ s){
  __shared__ float as[A_];
  int b=blockIdx.y, tid=threadIdx.x;
  for(int k=tid;k<A_;k+=128) as[k]=att[b*A_+k];
  __syncthreads();
  int l=blockIdx.x*128+tid;
  if(l<L_){
    float acc=0.f;
    const float4* cr=(const float4*)(ck+((long)(b*L_+l))*A_);
#pragma unroll 5
    for(int i=0;i<A_/4;i++){ float4 c4=cr[i];
      acc+=as[4*i]*c4.x+as[4*i+1]*c4.y+as[4*i+2]*c4.z+as[4*i+3]*c4.w; }
    s[b*L_+l]=mask[b*L_+l]?-1e9f:acc;
  }
}

// ---- vocab[b,v] = att[b,:] . out_W[v,:] + out_b[v] -> d_out[b,t,v] ----
__global__ __launch_bounds__(256) void k_vocab(const float* __restrict__ att,
    const float* __restrict__ W, const float* __restrict__ bias, int t,
    float* __restrict__ dout){
  __shared__ float as[B_*A_];
  int tid=threadIdx.x;
  for(int k=tid;k<B_*A_;k+=256) as[k]=att[k];
  __syncthreads();
  int v=blockIdx.x*256+tid;
  if(v>=V_) return;
  float acc[B_];
#pragma unroll
  for(int b=0;b<B_;b++) acc[b]=0.f;
  const float4* wr=(const float4*)(W+(long)v*A_);
  for(int i=0;i<A_/4;i++){
    float4 w=wr[i];
    int a=4*i;
#pragma unroll
    for(int b=0;b<B_;b++){
      acc[b]+=as[b*A_+a]*w.x+as[b*A_+a+1]*w.y+as[b*A_+a+2]*w.z+as[b*A_+a+3]*w.w;
    }
  }
  float ob=bias[v];
#pragma unroll
  for(int b=0;b<B_;b++) dout[((long)(b*T_+t))*V_+v]=acc[b]+ob;
}

// ---- scatter copy scores: dout[b,t,enc_in[b,l]] += softmax(scc)[l]*scale^2 ----
__global__ __launch_bounds__(128) void k_scatter(const float* __restrict__ s,
    const int* __restrict__ encin, const float* __restrict__ scale, int t,
    float* __restrict__ dout){
  __shared__ float row[L_];
  __shared__ float redm[2], reds[2];
  int b=blockIdx.y, tid=threadIdx.x;
  float lm=-3.0e38f;
  for(int l=tid;l<L_;l+=128){ float v=s[b*L_+l]; row[l]=v; lm=fmaxf(lm,v); }
  lm=waveMax(lm); if((tid&63)==0) redm[tid>>6]=lm;
  __syncthreads();
  float m=fmaxf(redm[0],redm[1]);
  float ls=0.f;
  for(int l=tid;l<L_;l+=128) ls+=expf(row[l]-m);
  ls=waveSum(ls); if((tid&63)==0) reds[tid>>6]=ls;
  __syncthreads();
  float S=reds[0]+reds[1];
  float f=scale[0]*scale[0]/S;
  int l=blockIdx.x*128+tid;
  if(l<L_){
    float p=expf(row[l]-m)*f;
    atomicAdd(dout+((long)(b*T_+t))*V_+encin[b*L_+l],p);
  }
}

// ---- argmax over vocab row (first-max wins), write syms as float ----
__global__ __launch_bounds__(256) void k_argmax(int t, float* __restrict__ dout){
  __shared__ float vs[256];
  __shared__ int is[256];
  int b=blockIdx.x, tid=threadIdx.x;
  const float* row=dout+((long)(b*T_+t))*V_;
  float best=-3.0e38f; int bi=0;
  for(int v=tid;v<V_;v+=256){ float x=row[v]; if(x>best){best=x;bi=v;} }
  vs[tid]=best; is[tid]=bi;
  __syncthreads();
  for(int off=128;off>0;off>>=1){
    if(tid<off){
      float ov=vs[tid+off]; int oi=is[tid+off];
      if(ov>vs[tid]||(ov==vs[tid]&&oi<is[tid])){ vs[tid]=ov; is[tid]=oi; }
    }
    __syncthreads();
  }
  if(tid==0) dout[(long)B_*T_*V_+b*T_+t]=(float)is[0];
}

// ---- sel partials: score_f folded; part[b,j,h] = sum_chunk score_f_l * enc[b,l,h] ----
__global__ __launch_bounds__(512) void k_sel(const float* __restrict__ s,
    const int* __restrict__ encin, const int* __restrict__ inp, int t,
    const float* __restrict__ enc, float* __restrict__ part){
  __shared__ float e[L_];
  __shared__ float redm[8], reds[8], redq[8];
  int b=blockIdx.y, j=blockIdx.x, tid=threadIdx.x;
  int so=inp[b*T_+t];
  float lm=-3.0e38f;
  for(int l=tid;l<L_;l+=512){ float v=s[b*L_+l]; e[l]=v; lm=fmaxf(lm,v); }
  lm=waveMax(lm); if((tid&63)==0) redm[tid>>6]=lm;
  __syncthreads();
  float m=redm[0];
#pragma unroll
  for(int w2=1;w2<8;w2++) m=fmaxf(m,redm[w2]);
  float ls=0.f, lq=0.f;
  for(int l=tid;l<L_;l+=512){
    float ex=expf(e[l]-m);
    float pe_=(encin[b*L_+l]==so)?ex:0.f;
    e[l]=pe_; ls+=ex; lq+=pe_;
  }
  ls=waveSum(ls); lq=waveSum(lq);
  if((tid&63)==0){ reds[tid>>6]=ls; redq[tid>>6]=lq; }
  __syncthreads();
  float S=0.f,Q=0.f;
#pragma unroll
  for(int w2=0;w2<8;w2++){ S+=reds[w2]; Q+=redq[w2]; }
  float inv=1.0f/(Q+1e-8f*S);
  float acc=0.f;
  int l0=j*125;
  for(int l=l0;l<l0+125;l++) acc+=e[l]*enc[((long)(b*L_+l))*H_+tid];
  part[(b*8+j)*H_+tid]=acc*inv;
}

extern "C" void kernel_launch(void* const* d_in, const int* in_sizes, int n_in,
                              void* d_out, int out_size, void* d_ws, size_t ws_size,
                              hipStream_t stream){
  const int* enc_in=(const int*)d_in[0];
  const float* enc_out=(const float*)d_in[1];
  const unsigned char* enc_mask=(const unsigned char*)d_in[2];
  const int* inputs=(const int*)d_in[3];
  const float* embed=(const float*)d_in[4];
  const float* e1Wih=(const float*)d_in[5], *e1Whh=(const float*)d_in[6], *e1b=(const float*)d_in[7];
  const float* e2Wih=(const float*)d_in[8], *e2Whh=(const float*)d_in[9], *e2b=(const float*)d_in[10];
  const float* inW=(const float*)d_in[11], *inb=(const float*)d_in[12];
  const float* r1Wih=(const float*)d_in[13], *r1Whh=(const float*)d_in[14], *r1b=(const float*)d_in[15];
  const float* a1Wq=(const float*)d_in[16], *a1bq=(const float*)d_in[17];
  const float* a1Wk=(const float*)d_in[18];
  const float* a1Wv=(const float*)d_in[20], *a1bv=(const float*)d_in[21];
  const float* r2Wih=(const float*)d_in[22], *r2Whh=(const float*)d_in[23], *r2b=(const float*)d_in[24];
  const float* a2Wq=(const float*)d_in[25], *a2bq=(const float*)d_in[26];
  const float* a2Wk=(const float*)d_in[27];
  const float* a2Wv=(const float*)d_in[29], *a2bv=(const float*)d_in[30];
  const float* cW=(const float*)d_in[31], *cb=(const float*)d_in[32];
  const float* oW=(const float*)d_in[33], *ob=(const float*)d_in[34];
  const float* scale=(const float*)d_in[35];
  float* dout=(float*)d_out;
  float* w=(float*)d_ws;

  size_t off=0;
  float* copyK=w+off; off+=(size_t)B_*L_*A_;      // 12,000,000
  float* pe=w+off;    off+=T_*H_;
  float* st=w+off;    off+=16*B_*H_;               // 8 states x 2 parities
  float* att1=w+off;  off+=B_*A_;
  float* att2=w+off;  off+=B_*A_;
  float* qk=w+off;    off+=B_*H_;
  float* s1=w+off;    off+=B_*L_;
  float* scc=w+off;   off+=B_*L_;
  float* ctxp=w+off;  off+=B_*8*H_;
  float* selp=w+off;  off+=B_*8*H_;
  float* decin=w+off; off+=B_*H_;

  // zero everything after copyK (states, att carry, sel partials, scratch)
  hipMemsetAsync(pe,0,(off-(size_t)B_*L_*A_)*sizeof(float),stream);
  k_pe<<<T_,H_,0,stream>>>(pe);
  k_copyk<<<B_*L_,320,0,stream>>>(enc_out,cW,cb,copyK);

  auto S=[&](int i){ return st+(size_t)i*(B_*H_); };
  for(int t=0;t<T_;t++){
    int rp=t&1, wp=rp^1;
    float *eh1r=S(0+rp),*eh1w=S(0+wp),*ec1r=S(2+rp),*ec1w=S(2+wp);
    float *eh2r=S(4+rp),*eh2w=S(4+wp),*ec2r=S(6+rp),*ec2w=S(6+wp);
    float *h1r=S(8+rp),*h1w=S(8+wp),*c1r=S(10+rp),*c1w=S(10+wp);
    float *h2r=S(12+rp),*h2w=S(12+wp),*c2r=S(14+rp),*c2w=S(14+wp);

    k_lstm<E_,true><<<dim3(8,B_),256,0,stream>>>(nullptr,inputs,embed,t,eh1r,ec1r,eh1w,ec1w,e1Wih,e1Whh,e1b);
    k_lstm<H_,false><<<dim3(8,B_),256,0,stream>>>(eh1w,nullptr,nullptr,t,eh2r,ec2r,eh2w,ec2w,e2Wih,e2Whh,e2b);
    k_decin<<<dim3(2,B_),256,0,stream>>>(inputs,embed,t,eh2w,att2,selp,inW,inb,pe,decin);
    k_lstm<H_,false><<<dim3(8,B_),256,0,stream>>>(decin,nullptr,nullptr,t,h1r,c1r,h1w,c1w,r1Wih,r1Whh,r1b);
    k_q<<<B_,512,0,stream>>>(h1w,a1Wq,a1bq,a1Wk,qk);
    k_scores<<<dim3(8,B_),128,0,stream>>>(qk,enc_out,enc_mask,s1);
    k_ctx<<<dim3(8,B_),512,0,stream>>>(s1,enc_out,ctxp);
    k_atto<false><<<B_,512,0,stream>>>(ctxp,a1Wv,a1bv,nullptr,att1);
    k_lstm<A_,false><<<dim3(8,B_),256,0,stream>>>(att1,nullptr,nullptr,t,h2r,c2r,h2w,c2w,r2Wih,r2Whh,r2b);
    k_q<<<B_,512,0,stream>>>(h2w,a2Wq,a2bq,a2Wk,qk);
    k_scores<<<dim3(8,B_),128,0,stream>>>(qk,enc_out,enc_mask,s1);
    k_ctx<<<dim3(8,B_),512,0,stream>>>(s1,enc_out,ctxp);
    k_atto<true><<<B_,512,0,stream>>>(ctxp,a2Wv,a2bv,att1,att2);
    k_copysc<<<dim3(8,B_),128,0,stream>>>(att2,copyK,enc_mask,scc);
    k_vocab<<<(V_+255)/256,256,0,stream>>>(att2,oW,ob,t,dout);
    k_scatter<<<dim3(8,B_),128,0,stream>>>(scc,enc_in,scale,t,dout);
    k_argmax<<<B_,256,0,stream>>>(t,dout);
    k_sel<<<dim3(8,B_),512,0,stream>>>(scc,enc_in,inputs,t,enc_out,selp);
  }
}

// Round 2
// 18390.512 us; speedup vs baseline: 1.0185x; 1.0185x over previous
//
#include <hip/hip_runtime.h>
#include <math.h>

#define B_ 40
#define L_ 1000
#define H_ 512
#define A_ 300
#define T_ 20
#define E_ 300
#define V_ 78864
#define CIN_ 1624   // E + H + A + H
#define START_ 2

__device__ __forceinline__ float sigm(float x){ return 1.0f/(1.0f+expf(-x)); }

__device__ __forceinline__ float waveMax(float v){
#pragma unroll
  for(int o=32;o>0;o>>=1) v=fmaxf(v,__shfl_down(v,o));
  return v;
}
__device__ __forceinline__ float waveSum(float v){
#pragma unroll
  for(int o=32;o>0;o>>=1) v+=__shfl_down(v,o);
  return v;
}
__device__ __forceinline__ float waveSumXor(float v){
#pragma unroll
  for(int o=32;o>0;o>>=1) v+=__shfl_xor(v,o);
  return v;
}

// ---- positional encoding table [T,512] ----
__global__ void k_pe(float* __restrict__ pe){
  int t=blockIdx.x, d=threadIdx.x;
  float ex=(float)(2*(d>>1))/512.0f;
  float ang=(float)t/powf(10000.0f,ex);
  pe[t*H_+d]=(d&1)?cosf(ang):sinf(ang);
}

// ---- copyK[b,l,a] = tanh(enc[b,l,:].copy_W[a,:]+copy_b[a]); 16 l per block ----
__global__ __launch_bounds__(320) void k_copyk(const float* __restrict__ enc,
    const float* __restrict__ W, const float* __restrict__ bias, float* __restrict__ out){
  int b=blockIdx.y, l0=blockIdx.x*16, a=threadIdx.x;
  if(a>=A_) return;
  int lcnt=min(16,L_-l0);
  float acc[16];
  float bv=bias[a];
#pragma unroll
  for(int l=0;l<16;l++) acc[l]=bv;
  const float4* wr=(const float4*)(W+(long)a*H_);
  for(int i=0;i<H_/4;i++){
    float4 w=wr[i];
#pragma unroll
    for(int l=0;l<16;l++){
      int row=b*L_+min(l0+l,L_-1);           // clamp: avoid OOB read, write guarded
      float4 x=((const float4*)enc)[(long)row*(H_/4)+i];  // uniform addr -> s_load
      acc[l]+=x.x*w.x+x.y*w.y+x.z*w.z+x.w*w.w;
    }
  }
  for(int l=0;l<lcnt;l++) out[((long)(b*L_+l0+l))*A_+a]=tanhf(acc[l]);
}

// ---- LSTM cell: grid (8,B); block 256 = 4 gates x 64 units; x,h via uniform s_load ----
template<int XD, bool GATHER>
__global__ __launch_bounds__(256) void k_lstm(const float* __restrict__ xsrc,
    const int* __restrict__ inp, const float* __restrict__ embed, int t,
    const float* __restrict__ hr, const float* __restrict__ cr,
    float* __restrict__ hw, float* __restrict__ cw,
    const float* __restrict__ Wih, const float* __restrict__ Whh, const float* __restrict__ bias){
  __shared__ float g4[256];
  int b=blockIdx.y, hb=blockIdx.x, tid=threadIdx.x;
  const float4* xr4;
  if constexpr(GATHER){
    int si=(t==0)?START_:inp[b*T_+t-1];
    xr4=(const float4*)(embed+(long)si*XD);
  } else {
    xr4=(const float4*)(xsrc+(long)b*XD);
  }
  const float4* hr4=(const float4*)(hr+(long)b*H_);
  int gate=tid>>6, u=(hb<<6)+(tid&63), row=gate*H_+u;
  float acc=bias[row];
  const float4* wi=(const float4*)(Wih+(long)row*XD);
#pragma unroll 4
  for(int i=0;i<XD/4;i++){ float4 w=wi[i]; float4 x=xr4[i];
    acc+=x.x*w.x+x.y*w.y+x.z*w.z+x.w*w.w; }
  const float4* wh=(const float4*)(Whh+(long)row*H_);
#pragma unroll 4
  for(int i=0;i<H_/4;i++){ float4 w=wh[i]; float4 h4=hr4[i];
    acc+=h4.x*w.x+h4.y*w.y+h4.z*w.z+h4.w*w.w; }
  g4[tid]=acc;
  __syncthreads();
  if(tid<64){
    int uu=(hb<<6)+tid;
    float gi=g4[tid],gf=g4[64+tid],gg=g4[128+tid],go=g4[192+tid];
    float c=cr[b*H_+uu];
    float cn=sigm(gf)*c+sigm(gi)*tanhf(gg);
    hw[b*H_+uu]=sigm(go)*tanhf(cn);
    cw[b*H_+uu]=cn;
  }
}

// ---- dec_in[b,d] = concat(emb,eh2,att,sel).in_W[d,:]+in_b[d]+pe[t,d] ----
__global__ __launch_bounds__(256) void k_decin(const int* __restrict__ inp,
    const float* __restrict__ embed, int t,
    const float* __restrict__ eh2, const float* __restrict__ attprev,
    const float* __restrict__ selpart,
    const float* __restrict__ W, const float* __restrict__ bias,
    const float* __restrict__ pe, float* __restrict__ out){
  __shared__ float xs[CIN_];
  int b=blockIdx.y, tid=threadIdx.x;
  int si=(t==0)?START_:inp[b*T_+t-1];
  for(int k=tid;k<CIN_;k+=256){
    float v;
    if(k<E_) v=embed[(long)si*E_+k];
    else if(k<E_+H_) v=eh2[b*H_+k-E_];
    else if(k<E_+H_+A_) v=attprev[b*A_+k-(E_+H_)];
    else{
      int h=k-(E_+H_+A_);
      float s=0.f;
#pragma unroll
      for(int j=0;j<8;j++) s+=selpart[(b*8+j)*H_+h];
      v=s;
    }
    xs[k]=v;
  }
  __syncthreads();
  int d=blockIdx.x*256+tid;
  float acc=bias[d]+pe[t*H_+d];
  const float4* wr=(const float4*)(W+(long)d*CIN_);
#pragma unroll 2
  for(int i=0;i<CIN_/4;i++){ float4 w=wr[i];
    acc+=xs[4*i]*w.x+xs[4*i+1]*w.y+xs[4*i+2]*w.z+xs[4*i+3]*w.w; }
  out[b*H_+d]=acc;
}

// ---- q = h@Wq.T + bq ; qk[b,h] = sum_a q[a]*Wk[a,h] ----
__global__ __launch_bounds__(512) void k_q(const float* __restrict__ h,
    const float* __restrict__ Wq, const float* __restrict__ bq,
    const float* __restrict__ Wk, float* __restrict__ qk){
  __shared__ float hs[H_], qs[A_];
  int b=blockIdx.x, tid=threadIdx.x;
  hs[tid]=h[b*H_+tid];
  __syncthreads();
  if(tid<A_){
    float acc=bq[tid];
    const float4* wr=(const float4*)(Wq+(long)tid*H_);
#pragma unroll 4
    for(int i=0;i<H_/4;i++){ float4 w=wr[i];
      acc+=hs[4*i]*w.x+hs[4*i+1]*w.y+hs[4*i+2]*w.z+hs[4*i+3]*w.w; }
    qs[tid]=acc;
  }
  __syncthreads();
  float acc=0.f;
  for(int a=0;a<A_;a++) acc+=qs[a]*Wk[a*H_+tid];
  qk[b*H_+tid]=acc;
}

// ---- s[b,l] = qk[b,:].enc[b,l,:] masked; wave-per-l, coalesced ----
__global__ __launch_bounds__(256) void k_scores(const float* __restrict__ qk,
    const float* __restrict__ enc, const unsigned char* __restrict__ mask,
    float* __restrict__ s){
  __shared__ float qs[H_];
  int b=blockIdx.y, j=blockIdx.x, tid=threadIdx.x;
  qs[tid]=qk[b*H_+tid]; qs[tid+256]=qk[b*H_+tid+256];
  __syncthreads();
  int wv=tid>>6, lane=tid&63;
  const float4* qs4=(const float4*)qs;
  for(int i=0;i<32;i++){
    int idx=i*4+wv;
    if(idx>=125) break;
    int l=j*125+idx;
    const float4* er=(const float4*)(enc+((long)(b*L_+l))*H_);
    float4 q1=qs4[lane], e1=er[lane];
    float p=q1.x*e1.x+q1.y*e1.y+q1.z*e1.z+q1.w*e1.w;
    float4 q2=qs4[64+lane], e2=er[64+lane];
    p+=q2.x*e2.x+q2.y*e2.y+q2.z*e2.z+q2.w*e2.w;
    p=waveSumXor(p);
    if(lane==0) s[b*L_+l]=mask[b*L_+l]?-1e9f:p;
  }
}

// ---- ctx partial: softmax(s) folded; part[b,j,h]=sum_chunk p_l*enc[b,l,h] ----
__global__ __launch_bounds__(512) void k_ctx(const float* __restrict__ s,
    const float* __restrict__ enc, float* __restrict__ part){
  __shared__ float e[L_];
  __shared__ float redm[8], reds[8];
  int b=blockIdx.y, j=blockIdx.x, tid=threadIdx.x;
  float lm=-3.0e38f;
  for(int l=tid;l<L_;l+=512){ float v=s[b*L_+l]; e[l]=v; lm=fmaxf(lm,v); }
  lm=waveMax(lm); if((tid&63)==0) redm[tid>>6]=lm;
  __syncthreads();
  float m=redm[0];
#pragma unroll
  for(int w2=1;w2<8;w2++) m=fmaxf(m,redm[w2]);
  float ls=0.f;
  for(int l=tid;l<L_;l+=512){ float ex=expf(e[l]-m); e[l]=ex; ls+=ex; }
  ls=waveSum(ls); if((tid&63)==0) reds[tid>>6]=ls;
  __syncthreads();
  float S=0.f;
#pragma unroll
  for(int w2=0;w2<8;w2++) S+=reds[w2];
  float inv=1.0f/S;
  float acc=0.f;
  int l0=j*125;
  for(int l=l0;l<l0+125;l++) acc+=e[l]*enc[((long)(b*L_+l))*H_+tid];
  part[(b*8+j)*H_+tid]=acc*inv;
}

// ---- att[b,a] = ctx.Wv[a,:]+bv (+attprev); ADD variant also writes attT[a][b] ----
template<bool ADD>
__global__ __launch_bounds__(512) void k_atto(const float* __restrict__ part,
    const float* __restrict__ Wv, const float* __restrict__ bv,
    const float* __restrict__ attprev, float* __restrict__ out, float* __restrict__ outT){
  __shared__ float cs[H_];
  int b=blockIdx.x, tid=threadIdx.x;
  float c=0.f;
#pragma unroll
  for(int j=0;j<8;j++) c+=part[(b*8+j)*H_+tid];
  cs[tid]=c;
  __syncthreads();
  if(tid<A_){
    float acc=bv[tid];
    const float4* wr=(const float4*)(Wv+(long)tid*H_);
#pragma unroll 4
    for(int i=0;i<H_/4;i++){ float4 w=wr[i];
      acc+=cs[4*i]*w.x+cs[4*i+1]*w.y+cs[4*i+2]*w.z+cs[4*i+3]*w.w; }
    if constexpr(ADD) acc+=attprev[b*A_+tid];
    out[b*A_+tid]=acc;
    if constexpr(ADD) outT[tid*B_+b]=acc;
  }
}

// ---- copy scores: s[b,l]=att.copyK[b,l,:] masked; wave-per-l coalesced ----
__global__ __launch_bounds__(256) void k_copysc(const float* __restrict__ att,
    const float* __restrict__ ck, const unsigned char* __restrict__ mask,
    float* __restrict__ s){
  __shared__ float as[A_];
  int b=blockIdx.y, j=blockIdx.x, tid=threadIdx.x;
  for(int k=tid;k<A_;k+=256) as[k]=att[b*A_+k];
  __syncthreads();
  int wv=tid>>6, lane=tid&63;
  for(int i=0;i<32;i++){
    int idx=i*4+wv;
    if(idx>=125) break;
    int l=j*125+idx;
    const float* cr=ck+((long)(b*L_+l))*A_;
    float p=0.f;
#pragma unroll
    for(int it=0;it<4;it++){ int k=it*64+lane; p+=as[k]*cr[k]; }
    { int k=256+lane; if(k<A_) p+=as[k]*cr[k]; }
    p=waveSumXor(p);
    if(lane==0) s[b*L_+l]=mask[b*L_+l]?-1e9f:p;
  }
}

// ---- vocab: W-tile staged in LDS (lane-varying), attT via uniform s_load ----
__global__ __launch_bounds__(256) void k_vocab(const float* __restrict__ attT,
    const float* __restrict__ W, const float* __restrict__ bias, int t,
    float* __restrict__ dout){
  __shared__ float wt[256*33];
  int tid=threadIdx.x;
  int v=blockIdx.x*256+tid;
  bool ok=v<V_;
  int v0=blockIdx.x*256;
  float acc[B_];
#pragma unroll
  for(int b=0;b<B_;b++) acc[b]=0.f;
  // 9 full chunks of 32 a's, then tail of 12
  for(int c=0;c<10;c++){
    int a0=c*32;
    int aw=(c<9)?32:12;
    __syncthreads();
    if(c<9){
      for(int idx=tid;idx<256*32;idx+=256){
        int vr=idx>>5, ar=idx&31;
        float val=(v0+vr<V_)?W[(long)(v0+vr)*A_+a0+ar]:0.f;
        wt[vr*33+ar]=val;
      }
    } else {
      for(int idx=tid;idx<256*12;idx+=256){
        int vr=idx/12, ar=idx-vr*12;
        float val=(v0+vr<V_)?W[(long)(v0+vr)*A_+a0+ar]:0.f;
        wt[vr*33+ar]=val;
      }
    }
    __syncthreads();
    for(int a=0;a<aw;a++){
      float wv=wt[tid*33+a];
      const float4* at4=(const float4*)(attT+(long)(a0+a)*B_);  // uniform -> s_load
#pragma unroll
      for(int bq=0;bq<10;bq++){
        float4 t4=at4[bq];
        acc[4*bq+0]+=wv*t4.x; acc[4*bq+1]+=wv*t4.y;
        acc[4*bq+2]+=wv*t4.z; acc[4*bq+3]+=wv*t4.w;
      }
    }
  }
  if(ok){
    float ob=bias[v];
#pragma unroll
    for(int b=0;b<B_;b++) dout[((long)(b*T_+t))*V_+v]=acc[b]+ob;
  }
}

// ---- fused scatter + sel: one softmax pass over scc ----
__global__ __launch_bounds__(512) void k_scatsel(const float* __restrict__ s,
    const int* __restrict__ encin, const int* __restrict__ inp,
    const float* __restrict__ scale, int t,
    const float* __restrict__ enc, float* __restrict__ part,
    float* __restrict__ dout){
  __shared__ float e[L_], e2[L_];
  __shared__ float redm[8], reds[8], redq[8];
  int b=blockIdx.y, j=blockIdx.x, tid=threadIdx.x;
  int so=inp[b*T_+t];
  float lm=-3.0e38f;
  for(int l=tid;l<L_;l+=512){ float v=s[b*L_+l]; e[l]=v; lm=fmaxf(lm,v); }
  lm=waveMax(lm); if((tid&63)==0) redm[tid>>6]=lm;
  __syncthreads();
  float m=redm[0];
#pragma unroll
  for(int w2=1;w2<8;w2++) m=fmaxf(m,redm[w2]);
  float ls=0.f, lq=0.f;
  for(int l=tid;l<L_;l+=512){
    float ex=expf(e[l]-m);
    float pe_=(encin[b*L_+l]==so)?ex:0.f;
    e[l]=ex; e2[l]=pe_; ls+=ex; lq+=pe_;
  }
  ls=waveSum(ls); lq=waveSum(lq);
  if((tid&63)==0){ reds[tid>>6]=ls; redq[tid>>6]=lq; }
  __syncthreads();
  float S=0.f,Q=0.f;
#pragma unroll
  for(int w2=0;w2<8;w2++){ S+=reds[w2]; Q+=redq[w2]; }
  int l0=j*125;
  // scatter this block's chunk
  if(tid<125){
    int l=l0+tid;
    float f=scale[0]*scale[0]/S;
    float p=e[l]*f;
    atomicAdd(dout+((long)(b*T_+t))*V_+encin[b*L_+l],p);
  }
  // sel partial for this chunk
  float inv=1.0f/(Q+1e-8f*S);
  float acc=0.f;
  for(int l=l0;l<l0+125;l++) acc+=e2[l]*enc[((long)(b*L_+l))*H_+tid];
  part[(b*8+j)*H_+tid]=acc*inv;
}

// ---- argmax over vocab row (first-max wins), write syms as float ----
__global__ __launch_bounds__(256) void k_argmax(int t, float* __restrict__ dout){
  __shared__ float vs[256];
  __shared__ int is[256];
  int b=blockIdx.x, tid=threadIdx.x;
  const float* row=dout+((long)(b*T_+t))*V_;
  float best=-3.0e38f; int bi=0;
  for(int v=tid;v<V_;v+=256){ float x=row[v]; if(x>best){best=x;bi=v;} }
  vs[tid]=best; is[tid]=bi;
  __syncthreads();
  for(int off=128;off>0;off>>=1){
    if(tid<off){
      float ov=vs[tid+off]; int oi=is[tid+off];
      if(ov>vs[tid]||(ov==vs[tid]&&oi<is[tid])){ vs[tid]=ov; is[tid]=oi; }
    }
    __syncthreads();
  }
  if(tid==0) dout[(long)B_*T_*V_+b*T_+t]=(float)is[0];
}

extern "C" void kernel_launch(void* const* d_in, const int* in_sizes, int n_in,
                              void* d_out, int out_size, void* d_ws, size_t ws_size,
                              hipStream_t stream){
  const int* enc_in=(const int*)d_in[0];
  const float* enc_out=(const float*)d_in[1];
  const unsigned char* enc_mask=(const unsigned char*)d_in[2];
  const int* inputs=(const int*)d_in[3];
  const float* embed=(const float*)d_in[4];
  const float* e1Wih=(const float*)d_in[5], *e1Whh=(const float*)d_in[6], *e1b=(const float*)d_in[7];
  const float* e2Wih=(const float*)d_in[8], *e2Whh=(const float*)d_in[9], *e2b=(const float*)d_in[10];
  const float* inW=(const float*)d_in[11], *inb=(const float*)d_in[12];
  const float* r1Wih=(const float*)d_in[13], *r1Whh=(const float*)d_in[14], *r1b=(const float*)d_in[15];
  const float* a1Wq=(const float*)d_in[16], *a1bq=(const float*)d_in[17];
  const float* a1Wk=(const float*)d_in[18];
  const float* a1Wv=(const float*)d_in[20], *a1bv=(const float*)d_in[21];
  const float* r2Wih=(const float*)d_in[22], *r2Whh=(const float*)d_in[23], *r2b=(const float*)d_in[24];
  const float* a2Wq=(const float*)d_in[25], *a2bq=(const float*)d_in[26];
  const float* a2Wk=(const float*)d_in[27];
  const float* a2Wv=(const float*)d_in[29], *a2bv=(const float*)d_in[30];
  const float* cW=(const float*)d_in[31], *cb=(const float*)d_in[32];
  const float* oW=(const float*)d_in[33], *ob=(const float*)d_in[34];
  const float* scale=(const float*)d_in[35];
  float* dout=(float*)d_out;
  float* w=(float*)d_ws;

  size_t off=0;
  float* copyK=w+off; off+=(size_t)B_*L_*A_;      // 12,000,000
  float* pe=w+off;    off+=T_*H_;
  float* st=w+off;    off+=16*B_*H_;               // 8 states x 2 parities
  float* att1=w+off;  off+=B_*A_;
  float* att2=w+off;  off+=B_*A_;
  float* attT=w+off;  off+=A_*B_;                  // att2 transposed [a][b]
  float* qk=w+off;    off+=B_*H_;
  float* s1=w+off;    off+=B_*L_;
  float* scc=w+off;   off+=B_*L_;
  float* ctxp=w+off;  off+=B_*8*H_;
  float* selp=w+off;  off+=B_*8*H_;
  float* decin=w+off; off+=B_*H_;

  // zero states/att carry/sel partials/scratch (everything after copyK)
  hipMemsetAsync(pe,0,(off-(size_t)B_*L_*A_)*sizeof(float),stream);
  k_pe<<<T_,H_,0,stream>>>(pe);
  k_copyk<<<dim3((L_+15)/16,B_),320,0,stream>>>(enc_out,cW,cb,copyK);

  auto S=[&](int i){ return st+(size_t)i*(B_*H_); };
  for(int t=0;t<T_;t++){
    int rp=t&1, wp=rp^1;
    float *eh1r=S(0+rp),*eh1w=S(0+wp),*ec1r=S(2+rp),*ec1w=S(2+wp);
    float *eh2r=S(4+rp),*eh2w=S(4+wp),*ec2r=S(6+rp),*ec2w=S(6+wp);
    float *h1r=S(8+rp),*h1w=S(8+wp),*c1r=S(10+rp),*c1w=S(10+wp);
    float *h2r=S(12+rp),*h2w=S(12+wp),*c2r=S(14+rp),*c2w=S(14+wp);

    k_lstm<E_,true><<<dim3(8,B_),256,0,stream>>>(nullptr,inputs,embed,t,eh1r,ec1r,eh1w,ec1w,e1Wih,e1Whh,e1b);
    k_lstm<H_,false><<<dim3(8,B_),256,0,stream>>>(eh1w,nullptr,nullptr,t,eh2r,ec2r,eh2w,ec2w,e2Wih,e2Whh,e2b);
    k_decin<<<dim3(2,B_),256,0,stream>>>(inputs,embed,t,eh2w,att2,selp,inW,inb,pe,decin);
    k_lstm<H_,false><<<dim3(8,B_),256,0,stream>>>(decin,nullptr,nullptr,t,h1r,c1r,h1w,c1w,r1Wih,r1Whh,r1b);
    k_q<<<B_,512,0,stream>>>(h1w,a1Wq,a1bq,a1Wk,qk);
    k_scores<<<dim3(8,B_),256,0,stream>>>(qk,enc_out,enc_mask,s1);
    k_ctx<<<dim3(8,B_),512,0,stream>>>(s1,enc_out,ctxp);
    k_atto<false><<<B_,512,0,stream>>>(ctxp,a1Wv,a1bv,nullptr,att1,nullptr);
    k_lstm<A_,false><<<dim3(8,B_),256,0,stream>>>(att1,nullptr,nullptr,t,h2r,c2r,h2w,c2w,r2Wih,r2Whh,r2b);
    k_q<<<B_,512,0,stream>>>(h2w,a2Wq,a2bq,a2Wk,qk);
    k_scores<<<dim3(8,B_),256,0,stream>>>(qk,enc_out,enc_mask,s1);
    k_ctx<<<dim3(8,B_),512,0,stream>>>(s1,enc_out,ctxp);
    k_atto<true><<<B_,512,0,stream>>>(ctxp,a2Wv,a2bv,att1,att2,attT);
    k_copysc<<<dim3(8,B_),256,0,stream>>>(att2,copyK,enc_mask,scc);
    k_vocab<<<(V_+255)/256,256,0,stream>>>(attT,oW,ob,t,dout);
    k_scatsel<<<dim3(8,B_),512,0,stream>>>(scc,enc_in,inputs,scale,t,enc_out,selp,dout);
    k_argmax<<<B_,256,0,stream>>>(t,dout);
  }
}

// Round 3
// 17990.843 us; speedup vs baseline: 1.0411x; 1.0222x over previous
//
#include <hip/hip_runtime.h>
#include <math.h>

#define B_ 40
#define L_ 1000
#define H_ 512
#define A_ 300
#define T_ 20
#define E_ 300
#define V_ 78864
#define START_ 2

#define NBLK 256
#define NTHR 512

// ---------------- workspace layout (float offsets) ----------------
#define OFF_COPYK 0ul
#define OFF_M1T   12000000ul
#define OFF_M2T   12262144ul
#define OFF_BQK1  12524288ul
#define OFF_BQK2  12524800ul
#define OFF_QK    12525312ul
#define OFF_DEC   12545792ul
#define OFF_ATT1  12566272ul
#define OFF_ATTT  12578272ul
#define OFF_CPART 12590272ul
#define OFF_CSTAT 12713152ul
#define OFF_SCC   12713664ul
#define OFF_STT   12753664ul   /* zero region starts here */
#define OFF_ATT2  13081344ul
#define OFF_SELP  13093344ul
#define OFF_CNT   13216224ul
#define WS_END    13216288ul

struct P {
  const int* enc_in; const float* enc; const unsigned char* mask; const int* inputs;
  const float* embed;
  const float *e1Wih,*e1Whh,*e1b,*e2Wih,*e2Whh,*e2b;
  const float *inW,*inb;
  const float *r1Wih,*r1Whh,*r1b;
  const float *a1Wq,*a1bq,*a1Wk,*a1Wv,*a1bv;
  const float *r2Wih,*r2Whh,*r2b;
  const float *a2Wq,*a2bq,*a2Wk,*a2Wv,*a2bv;
  const float *cW,*cb,*oW,*ob,*scale;
  float* dout;
  float *copyK,*M1T,*M2T,*bqk1,*bqk2,*qk,*dec,*att1,*attT,*cpart,*cstat,*scc,*stt,*att2,*selp;
  unsigned* cnt;
};

__device__ __forceinline__ float sigm(float x){ return 1.0f/(1.0f+expf(-x)); }

__device__ __forceinline__ float wredSum(float v){
#pragma unroll
  for(int o=32;o>0;o>>=1) v+=__shfl_xor(v,o);
  return v;
}
__device__ __forceinline__ float wredMax(float v){
#pragma unroll
  for(int o=32;o>0;o>>=1) v=fmaxf(v,__shfl_xor(v,o));
  return v;
}

// device-scope grid barrier: monotone counter, memset to 0 before launch
__device__ __forceinline__ void gbar(unsigned* cnt, unsigned target){
  __syncthreads();
  if(threadIdx.x==0){
    __hip_atomic_fetch_add(cnt,1u,__ATOMIC_RELEASE,__HIP_MEMORY_SCOPE_AGENT);
    while(__hip_atomic_load(cnt,__ATOMIC_RELAXED,__HIP_MEMORY_SCOPE_AGENT)<target){
      __builtin_amdgcn_s_sleep(1);
    }
    (void)__hip_atomic_load(cnt,__ATOMIC_ACQUIRE,__HIP_MEMORY_SCOPE_AGENT);
  }
  __syncthreads();
}

// batched-40 GEMV accumulate over one input segment.
// xs: LDS [40*257]; each wave owns one W row (uniform); lane<40 = batch index.
// kq/nq: K-split among waves sharing a row (nq=1 for none).
template<typename SRC>
static __device__ __forceinline__ void gv_accum(float* xs,int K,const float* Wrow,
    float& acc,int lane,int kq,int nq,SRC src){
  for(int k0=0;k0<K;k0+=256){
    int ch=min(256,K-k0);
    __syncthreads();
    for(int i=threadIdx.x;i<40*ch;i+=NTHR){
      int bb=i/ch, kk=i-bb*ch;
      xs[bb*257+kk]=src(bb,k0+kk);
    }
    __syncthreads();
    if(lane<40){
#pragma unroll 4
      for(int k=kq;k<ch;k+=nq) acc+=Wrow[k0+k]*xs[lane*257+k];
    }
  }
}

// one LSTM cell for all 40 b: block owns 2 units x 4 gates (8 waves)
static __device__ void lstm_ph(const P& p,float* SH,float* gld,int t,
    const float* Wih,int XD,const float* Whh,const float* bias,
    const float* xvec,bool gather,
    const float* hr,const float* cr,float* hw,float* cw){
  int tid=threadIdx.x,w=tid>>6,lane=tid&63;
  int gate=w&3,usub=w>>2;
  int row=gate*H_+(blockIdx.x*2+usub);
  int rowu=__builtin_amdgcn_readfirstlane(row);
  float acc=bias[rowu];
  const float* W1=Wih+(size_t)rowu*XD;
  if(gather){
    const int* inp=p.inputs; const float* emb=p.embed; int tt=t;
    gv_accum(SH,XD,W1,acc,lane,0,1,[=](int bb,int kk)->float{
      int si=(tt==0)?START_:inp[bb*T_+tt-1];
      return emb[(size_t)si*E_+kk];});
  }else{
    gv_accum(SH,XD,W1,acc,lane,0,1,[=](int bb,int kk)->float{
      return xvec[(size_t)bb*XD+kk];});
  }
  const float* W2=Whh+(size_t)rowu*H_;
  gv_accum(SH,H_,W2,acc,lane,0,1,[=](int bb,int kk)->float{
    return hr[bb*H_+kk];});
  gld[w*64+lane]=acc;
  __syncthreads();
  if(w<2&&lane<40){
    int u=blockIdx.x*2+w,b=lane;
    float gi=gld[(w*4+0)*64+b],gf=gld[(w*4+1)*64+b],gg=gld[(w*4+2)*64+b],go=gld[(w*4+3)*64+b];
    float c=cr[b*H_+u];
    float cn=sigm(gf)*c+sigm(gi)*tanhf(gg);
    hw[b*H_+u]=sigm(go)*tanhf(cn);
    cw[b*H_+u]=cn;
  }
  __syncthreads();
}

// qk[b][h'] = bqk[h'] + sum_h hsrc[b][h] * MT[h'][h]
static __device__ void qk_ph(const P& p,float* SH,const float* hsrc,
    const float* MT,const float* bqk){
  int tid=threadIdx.x;
  if(blockIdx.x>=240) return;
  int b=blockIdx.x/6, j=blockIdx.x%6;
  SH[tid]=hsrc[b*H_+tid];
  __syncthreads();
  int h0=j*86, hc=min(86,H_-h0);
  if(tid<hc){
    int hp=h0+tid;
    float a=bqk[hp];
    const float4* mr=(const float4*)(MT+(size_t)hp*H_);
#pragma unroll 8
    for(int i=0;i<H_/4;i++){
      float4 m4=mr[i];
      a+=SH[4*i]*m4.x+SH[4*i+1]*m4.y+SH[4*i+2]*m4.z+SH[4*i+3]*m4.w;
    }
    p.qk[b*H_+hp]=a;
  }
}

// fused scores + online-softmax-weighted ctx partial for chunk j
static __device__ void scctx_ph(const P& p,float* SH,float* red){
  int tid=threadIdx.x,w=tid>>6,lane=tid&63;
  if(blockIdx.x>=240) return;
  int b=blockIdx.x/6, j=blockIdx.x%6;
  int l0=j*167, lcnt=min(167,L_-l0);
  const float* qrow=p.qk+b*H_;
  float4 q0=*(const float4*)(qrow+lane*8);
  float4 q1=*(const float4*)(qrow+lane*8+4);
  float m=-3.0e38f,S=0.f;
  float4 a0=make_float4(0.f,0.f,0.f,0.f), a1=a0;
  for(int l=l0+w;l<l0+lcnt;l+=8){
    const float4* er=(const float4*)(p.enc+((size_t)(b*L_+l))*H_);
    float4 e0=er[lane*2], e1=er[lane*2+1];
    float pp=q0.x*e0.x+q0.y*e0.y+q0.z*e0.z+q0.w*e0.w
            +q1.x*e1.x+q1.y*e1.y+q1.z*e1.z+q1.w*e1.w;
    pp=wredSum(pp);
    if(p.mask[b*L_+l]) pp=-1e9f;
    float mn=fmaxf(m,pp);
    float sc=expf(m-mn), pe=expf(pp-mn);
    S=S*sc+pe;
    a0.x=a0.x*sc+pe*e0.x; a0.y=a0.y*sc+pe*e0.y; a0.z=a0.z*sc+pe*e0.z; a0.w=a0.w*sc+pe*e0.w;
    a1.x=a1.x*sc+pe*e1.x; a1.y=a1.y*sc+pe*e1.y; a1.z=a1.z*sc+pe*e1.z; a1.w=a1.w*sc+pe*e1.w;
    m=mn;
  }
  *(float4*)(SH+w*H_+lane*8)=a0;
  *(float4*)(SH+w*H_+lane*8+4)=a1;
  if(lane==0){red[w]=m; red[8+w]=S;}
  __syncthreads();
  float mb=red[0];
#pragma unroll
  for(int q=1;q<8;q++) mb=fmaxf(mb,red[q]);
  float Sb=0.f;
#pragma unroll
  for(int q=0;q<8;q++) Sb+=red[8+q]*expf(red[q]-mb);
  float pv=0.f;
#pragma unroll
  for(int q=0;q<8;q++) pv+=expf(red[q]-mb)*SH[q*H_+tid];
  p.cpart[(size_t)(b*6+j)*H_+tid]=pv;
  if(tid==0){p.cstat[(b*6+j)*2]=mb; p.cstat[(b*6+j)*2+1]=Sb;}
}

// combine 6 ctx partials, project through Wv (+bv) -> att
static __device__ void atto_ph(const P& p,float* SH,const float* Wv,const float* bv,bool ADD){
  int tid=threadIdx.x;
  if(blockIdx.x>=40) return;
  int b=blockIdx.x;
  float mb=-3.0e38f;
#pragma unroll
  for(int j=0;j<6;j++) mb=fmaxf(mb,p.cstat[(b*6+j)*2]);
  float Sb=0.f;
#pragma unroll
  for(int j=0;j<6;j++) Sb+=p.cstat[(b*6+j)*2+1]*expf(p.cstat[(b*6+j)*2]-mb);
  float inv=1.0f/Sb;
  float cx=0.f;
#pragma unroll
  for(int j=0;j<6;j++) cx+=expf(p.cstat[(b*6+j)*2]-mb)*p.cpart[(size_t)(b*6+j)*H_+tid];
  SH[tid]=cx*inv;
  __syncthreads();
  if(tid<A_){
    float a=bv[tid];
    const float4* wr=(const float4*)(Wv+(size_t)tid*H_);
#pragma unroll 8
    for(int i=0;i<H_/4;i++){
      float4 w4=wr[i];
      a+=SH[4*i]*w4.x+SH[4*i+1]*w4.y+SH[4*i+2]*w4.z+SH[4*i+3]*w4.w;
    }
    if(ADD){ a+=p.att1[b*A_+tid]; p.att2[b*A_+tid]=a; p.attT[tid*B_+b]=a; }
    else p.att1[b*A_+tid]=a;
  }
}

// copy scores: scc[b][l] = att2[b] . copyK[b,l,:], masked
static __device__ void copysc_ph(const P& p){
  int tid=threadIdx.x,w=tid>>6,lane=tid&63;
  if(blockIdx.x>=240) return;
  int b=blockIdx.x/6, j=blockIdx.x%6;
  int l0=j*167, lcnt=min(167,L_-l0);
  float4 r0=*(const float4*)(p.att2+b*A_+lane*4);
  float4 r1=make_float4(0.f,0.f,0.f,0.f);
  if(lane<11) r1=*(const float4*)(p.att2+b*A_+256+lane*4);
  for(int l=l0+w;l<l0+lcnt;l+=8){
    const float4* cr=(const float4*)(p.copyK+((size_t)(b*L_+l))*A_);
    float4 c0=cr[lane];
    float pp=r0.x*c0.x+r0.y*c0.y+r0.z*c0.z+r0.w*c0.w;
    if(lane<11){
      float4 c1=cr[64+lane];
      pp+=r1.x*c1.x+r1.y*c1.y+r1.z*c1.z+r1.w*c1.w;
    }
    pp=wredSum(pp);
    if(lane==0) p.scc[b*L_+l]=p.mask[b*L_+l]?-1e9f:pp;
  }
}

// vocab rows v0..v0+311: acc over 40 b; W tile in LDS, attT via uniform s_load
static __device__ void vocab_ph(const P& p,float* SH,int t){
  int tid=threadIdx.x;
  int v0=blockIdx.x*312;
  if(v0>=V_) return;
  int vcnt=min(312,V_-v0);
  float acc[40];
#pragma unroll
  for(int b=0;b<40;b++) acc[b]=0.f;
  for(int c=0;c<10;c++){
    int a0=c*32, aw=min(32,A_-a0);
    __syncthreads();
    for(int i=tid;i<vcnt*aw;i+=NTHR){
      int vr=i/aw, ac=i-vr*aw;
      SH[vr*33+ac]=p.oW[(size_t)(v0+vr)*A_+a0+ac];
    }
    __syncthreads();
    if(tid<vcnt){
      for(int ac=0;ac<aw;ac++){
        float wv=SH[tid*33+ac];
        const float* at=p.attT+(a0+ac)*B_;
#pragma unroll
        for(int bq=0;bq<10;bq++){
          float4 t4=*(const float4*)(at+bq*4);
          acc[bq*4+0]+=wv*t4.x; acc[bq*4+1]+=wv*t4.y;
          acc[bq*4+2]+=wv*t4.z; acc[bq*4+3]+=wv*t4.w;
        }
      }
    }
  }
  if(tid<vcnt){
    int v=v0+tid;
    float obv=p.ob[v];
#pragma unroll
    for(int b=0;b<40;b++) p.dout[((size_t)(b*T_+t))*V_+v]=acc[b]+obv;
  }
}

// softmax(scc) stats (redundant per chunk) + scatter adds + sel partial
static __device__ void scatsel_ph(const P& p,float* SH,float* red,int t){
  int tid=threadIdx.x,w=tid>>6,lane=tid&63;
  if(blockIdx.x>=240) return;
  int b=blockIdx.x/6, j=blockIdx.x%6;
  int l0=j*167, lcnt=min(167,L_-l0);
  for(int i=tid;i<L_;i+=NTHR) SH[i]=p.scc[b*L_+i];
  __syncthreads();
  float lm=-3.0e38f;
  for(int i=tid;i<L_;i+=NTHR) lm=fmaxf(lm,SH[i]);
  lm=wredMax(lm);
  if(lane==0) red[w]=lm;
  __syncthreads();
  float m=red[0];
#pragma unroll
  for(int q=1;q<8;q++) m=fmaxf(m,red[q]);
  __syncthreads();
  int so=p.inputs[b*T_+t];
  float ls=0.f,lq=0.f;
  for(int i=tid;i<L_;i+=NTHR){
    float exv=expf(SH[i]-m);
    ls+=exv;
    if(p.enc_in[b*L_+i]==so) lq+=exv;
  }
  ls=wredSum(ls); lq=wredSum(lq);
  if(lane==0){red[w]=ls; red[8+w]=lq;}
  __syncthreads();
  float S=0.f,Q=0.f;
#pragma unroll
  for(int q=0;q<8;q++){S+=red[q];Q+=red[8+q];}
  if(tid<lcnt){
    int l=l0+tid;
    float exv=expf(SH[l]-m);
    SH[1024+tid]=(p.enc_in[b*L_+l]==so)?exv:0.f;
    float sc2=p.scale[0]*p.scale[0];
    atomicAdd(p.dout+((size_t)(b*T_+t))*V_+p.enc_in[b*L_+l], exv*sc2/S);
  }
  __syncthreads();
  float inv=1.0f/(Q+1e-8f*S);
  float a=0.f;
  for(int li=0;li<lcnt;li++)
    a+=SH[1024+li]*p.enc[((size_t)(b*L_+l0+li))*H_+tid];
  p.selp[(size_t)(b*6+j)*H_+tid]=a*inv;
}

// per-b argmax over full vocab row (first max wins) -> syms
static __device__ void argmax_ph(const P& p,float* SH,int t){
  int tid=threadIdx.x;
  if(blockIdx.x>=40) return;
  int b=blockIdx.x;
  const float* row=p.dout+((size_t)(b*T_+t))*V_;
  float best=-3.0e38f; int bi=0;
  for(int i4=tid;i4<V_/4;i4+=NTHR){
    float4 x=((const float4*)row)[i4];
    int base=i4*4;
    if(x.x>best){best=x.x;bi=base;}
    if(x.y>best){best=x.y;bi=base+1;}
    if(x.z>best){best=x.z;bi=base+2;}
    if(x.w>best){best=x.w;bi=base+3;}
  }
  int* isa=(int*)(SH+512);
  SH[tid]=best; isa[tid]=bi;
  __syncthreads();
  for(int off=256;off>0;off>>=1){
    if(tid<off){
      float ov=SH[tid+off]; int oi=isa[tid+off];
      if(ov>SH[tid]||(ov==SH[tid]&&oi<isa[tid])){SH[tid]=ov; isa[tid]=oi;}
    }
    __syncthreads();
  }
  if(tid==0) p.dout[(size_t)B_*T_*V_+b*T_+t]=(float)isa[0];
}

__global__ __launch_bounds__(NTHR,2) void k_persist(P p){
  __shared__ float SH[10320];
  __shared__ float gld[512];
  __shared__ float red[16];
  int blk=blockIdx.x, tid=threadIdx.x;
  unsigned bt=0;
#define BARR() do{bt++; gbar(p.cnt,bt*(unsigned)NBLK);}while(0)

  // ===== PREP: M1T/M2T = Wq^T@Wk (transposed), bqk = bq@Wk =====
  {
    int mm=blk>>7, r0=(blk&127)*4;
    const float* Wq = mm? p.a2Wq : p.a1Wq;
    const float* Wk = mm? p.a2Wk : p.a1Wk;
    float* MT = mm? p.M2T : p.M1T;
    float s0=0.f,s1=0.f,s2=0.f,s3=0.f;
    for(int a=0;a<A_;a++){
      float wq=Wq[a*H_+tid];
      s0+=wq*Wk[a*H_+r0+0];
      s1+=wq*Wk[a*H_+r0+1];
      s2+=wq*Wk[a*H_+r0+2];
      s3+=wq*Wk[a*H_+r0+3];
    }
    MT[(size_t)(r0+0)*H_+tid]=s0;
    MT[(size_t)(r0+1)*H_+tid]=s1;
    MT[(size_t)(r0+2)*H_+tid]=s2;
    MT[(size_t)(r0+3)*H_+tid]=s3;
    if((blk&127)==0){
      const float* bq = mm? p.a2bq : p.a1bq;
      float ab=0.f;
      for(int a=0;a<A_;a++) ab+=bq[a]*Wk[a*H_+tid];
      (mm? p.bqk2 : p.bqk1)[tid]=ab;
    }
  }
  // ===== PREP: copyK = tanh(enc @ cW^T + cb) =====
  for(int item=blk;item<B_*63;item+=NBLK){
    int b=item/63, lt=item-b*63;
    int l0=lt*16, lcnt=min(16,L_-l0);
    float acc[16];
    float bv=(tid<A_)?p.cb[tid]:0.f;
#pragma unroll
    for(int l=0;l<16;l++) acc[l]=bv;
    for(int k0=0;k0<H_;k0+=32){
      __syncthreads();
      for(int i=tid;i<A_*32;i+=NTHR){
        int a=i>>5,kc=i&31;
        SH[a*33+kc]=p.cW[(size_t)a*H_+k0+kc];
      }
      __syncthreads();
      if(tid<A_){
#pragma unroll
        for(int l=0;l<16;l++){
          if(l<lcnt){
            const float* es=p.enc+((size_t)(b*L_+l0+l))*H_+k0;
            float al=acc[l];
#pragma unroll
            for(int kc=0;kc<32;kc++) al+=SH[tid*33+kc]*es[kc];
            acc[l]=al;
          }
        }
      }
    }
    if(tid<A_){
#pragma unroll
      for(int l=0;l<16;l++)
        if(l<lcnt) p.copyK[((size_t)(b*L_+l0+l))*A_+tid]=tanhf(acc[l]);
    }
  }
  BARR();

  // ===== decoder steps =====
  for(int t=0;t<T_;t++){
    int rp=t&1, wp=rp^1;
    float* stt=p.stt;
    auto SL=[&](int i,int par){ return stt+((size_t)(i*2+par))*(B_*H_); };
    float *eh1r=SL(0,rp),*eh1w=SL(0,wp),*ec1r=SL(1,rp),*ec1w=SL(1,wp);
    float *eh2r=SL(2,rp),*eh2w=SL(2,wp),*ec2r=SL(3,rp),*ec2w=SL(3,wp);
    float *h1r=SL(4,rp),*h1w=SL(4,wp),*c1r=SL(5,rp),*c1w=SL(5,wp);
    float *h2r=SL(6,rp),*h2w=SL(6,wp),*c2r=SL(7,rp),*c2w=SL(7,wp);

    lstm_ph(p,SH,gld,t,p.e1Wih,E_,p.e1Whh,p.e1b,nullptr,true ,eh1r,ec1r,eh1w,ec1w); BARR();
    lstm_ph(p,SH,gld,t,p.e2Wih,H_,p.e2Whh,p.e2b,eh1w  ,false,eh2r,ec2r,eh2w,ec2w); BARR();

    { // dec_in = concat(emb, eh2, att2_prev, sel_prev) @ in_W^T + in_b + pe
      int w=tid>>6,lane=tid&63;
      int usub=w>>2, kq=w&3;
      int unit=blk*2+usub;
      int rowu=__builtin_amdgcn_readfirstlane(unit);
      float acc=0.f;
      const float* Wr=p.inW+(size_t)rowu*1624;
      const int* inp=p.inputs; const float* emb=p.embed;
      const float* e2=eh2w; const float* a2c=p.att2; const float* sp=p.selp;
      int tt=t;
      gv_accum(SH,1624,Wr,acc,lane,kq,4,[=](int bb,int kk)->float{
        if(kk<E_){int si=(tt==0)?START_:inp[bb*T_+tt-1];return emb[(size_t)si*E_+kk];}
        else if(kk<E_+H_) return e2[bb*H_+kk-E_];
        else if(kk<E_+H_+A_) return a2c[bb*A_+kk-(E_+H_)];
        else{
          int hh=kk-(E_+H_+A_); float s=0.f;
#pragma unroll
          for(int jj=0;jj<6;jj++) s+=sp[(size_t)(bb*6+jj)*H_+hh];
          return s;
        }
      });
      gld[(usub*4+kq)*64+lane]=acc;
      __syncthreads();
      if(w<2&&lane<40){
        int u=blk*2+w;
        float s=gld[(w*4+0)*64+lane]+gld[(w*4+1)*64+lane]
               +gld[(w*4+2)*64+lane]+gld[(w*4+3)*64+lane];
        float ex=(float)(2*(u>>1))/512.0f;
        float ang=(float)t/powf(10000.0f,ex);
        s+=p.inb[u]+((u&1)?cosf(ang):sinf(ang));
        p.dec[lane*H_+u]=s;
      }
      __syncthreads();
    }
    BARR();

    lstm_ph(p,SH,gld,t,p.r1Wih,H_,p.r1Whh,p.r1b,p.dec ,false,h1r,c1r,h1w,c1w); BARR();
    qk_ph(p,SH,h1w,p.M1T,p.bqk1);                                              BARR();
    scctx_ph(p,SH,red);                                                        BARR();
    atto_ph(p,SH,p.a1Wv,p.a1bv,false);                                         BARR();
    lstm_ph(p,SH,gld,t,p.r2Wih,A_,p.r2Whh,p.r2b,p.att1,false,h2r,c2r,h2w,c2w); BARR();
    qk_ph(p,SH,h2w,p.M2T,p.bqk2);                                              BARR();
    scctx_ph(p,SH,red);                                                        BARR();
    atto_ph(p,SH,p.a2Wv,p.a2bv,true);                                          BARR();
    copysc_ph(p);                                                              BARR();
    vocab_ph(p,SH,t);                                                          BARR();
    scatsel_ph(p,SH,red,t);                                                    BARR();
    argmax_ph(p,SH,t);
    // no barrier needed: next step's elmo1 touches no buffers argmax uses
  }
#undef BARR
}

extern "C" void kernel_launch(void* const* d_in, const int* in_sizes, int n_in,
                              void* d_out, int out_size, void* d_ws, size_t ws_size,
                              hipStream_t stream){
  P p;
  p.enc_in=(const int*)d_in[0];
  p.enc   =(const float*)d_in[1];
  p.mask  =(const unsigned char*)d_in[2];
  p.inputs=(const int*)d_in[3];
  p.embed =(const float*)d_in[4];
  p.e1Wih=(const float*)d_in[5];  p.e1Whh=(const float*)d_in[6];  p.e1b=(const float*)d_in[7];
  p.e2Wih=(const float*)d_in[8];  p.e2Whh=(const float*)d_in[9];  p.e2b=(const float*)d_in[10];
  p.inW  =(const float*)d_in[11]; p.inb  =(const float*)d_in[12];
  p.r1Wih=(const float*)d_in[13]; p.r1Whh=(const float*)d_in[14]; p.r1b=(const float*)d_in[15];
  p.a1Wq =(const float*)d_in[16]; p.a1bq =(const float*)d_in[17];
  p.a1Wk =(const float*)d_in[18];
  p.a1Wv =(const float*)d_in[20]; p.a1bv =(const float*)d_in[21];
  p.r2Wih=(const float*)d_in[22]; p.r2Whh=(const float*)d_in[23]; p.r2b=(const float*)d_in[24];
  p.a2Wq =(const float*)d_in[25]; p.a2bq =(const float*)d_in[26];
  p.a2Wk =(const float*)d_in[27];
  p.a2Wv =(const float*)d_in[29]; p.a2bv =(const float*)d_in[30];
  p.cW   =(const float*)d_in[31]; p.cb   =(const float*)d_in[32];
  p.oW   =(const float*)d_in[33]; p.ob   =(const float*)d_in[34];
  p.scale=(const float*)d_in[35];
  p.dout=(float*)d_out;

  float* w=(float*)d_ws;
  p.copyK=w+OFF_COPYK;
  p.M1T  =w+OFF_M1T;   p.M2T =w+OFF_M2T;
  p.bqk1 =w+OFF_BQK1;  p.bqk2=w+OFF_BQK2;
  p.qk   =w+OFF_QK;    p.dec =w+OFF_DEC;
  p.att1 =w+OFF_ATT1;  p.attT=w+OFF_ATTT;
  p.cpart=w+OFF_CPART; p.cstat=w+OFF_CSTAT;
  p.scc  =w+OFF_SCC;   p.stt =w+OFF_STT;
  p.att2 =w+OFF_ATT2;  p.selp=w+OFF_SELP;
  p.cnt  =(unsigned*)(w+OFF_CNT);

  // zero: LSTM states (both parities), att2 carry, sel partials, barrier counter
  hipMemsetAsync(w+OFF_STT,0,(WS_END-OFF_STT)*sizeof(float),stream);
  k_persist<<<NBLK,NTHR,0,stream>>>(p);
}